// Round 2
// 452.599 us; speedup vs baseline: 1.1738x; 1.1738x over previous
//
#include <hip/hip_runtime.h>
#include <hip/hip_bf16.h>
#include <math.h>

#define H 128

typedef __bf16 bf16x8 __attribute__((ext_vector_type(8)));
typedef float f32x4 __attribute__((ext_vector_type(4)));
typedef __hip_bfloat16 bf16;

__device__ __forceinline__ bf16x8 ldb8(const bf16* p) {
  return *(const bf16x8*)(const void*)p;
}
__device__ __forceinline__ float fsig(float x) {
  return __fdividef(1.f, 1.f + __expf(-x));
}
__device__ __forceinline__ float ftanh(float x) {
  float x2 = fminf(fmaxf(2.f * x, -80.f), 80.f);
  float t = __expf(x2);
  return __fdividef(t - 1.f, t + 1.f);
}

// fused prep: h0 init (zero-pad x), whh->bf16, G = fold(W, w_ih), deg = 0
__global__ __launch_bounds__(256) void k_prep(const float* __restrict__ x,
                                              bf16* __restrict__ hb,
                                              const float* __restrict__ whh,
                                              bf16* __restrict__ whhb,
                                              const float* __restrict__ W,
                                              const float* __restrict__ wih,
                                              bf16* __restrict__ G,
                                              int* __restrict__ deg, int N) {
  int i = blockIdx.x * 256 + threadIdx.x;
  int NH_ = N * H;
  if (i < NH_) {
    int f = i & (H - 1);
    int n = i >> 7;
    hb[i] = __float2bfloat16((f < 64) ? x[n * 64 + f] : 0.f);
    return;
  }
  i -= NH_;
  if (i < 3 * H * H) {
    whhb[i] = __float2bfloat16(whh[i]);
    return;
  }
  i -= 3 * H * H;
  if (i < 3 * 3 * H * H) {
    int l = i / (3 * H * H);
    int r = i % (3 * H * H);
    int j = r >> 7;
    int k = r & (H - 1);
    const float4* a = (const float4*)(wih + (size_t)j * H);
    const float4* b = (const float4*)(W + (size_t)l * H * H + (size_t)k * H);
    float s = 0.f;
#pragma unroll
    for (int q = 0; q < 32; q++) {
      float4 av = a[q], bv = b[q];
      s += av.x * bv.x + av.y * bv.y + av.z * bv.z + av.w * bv.w;
    }
    G[i] = __float2bfloat16(s);
    return;
  }
  i -= 3 * 3 * H * H;
  if (i < N) deg[i] = 0;
}

// ---------- CSR build ----------
__global__ __launch_bounds__(256) void k_count(const int* __restrict__ dst,
                                               int* __restrict__ deg, int E) {
  int e = blockIdx.x * 256 + threadIdx.x;
  if (e < E) atomicAdd(&deg[dst[e]], 1);
}

__global__ __launch_bounds__(256) void k_bsum(const int* __restrict__ deg,
                                              int* __restrict__ bsums, int N) {
  __shared__ int ws[4];
  int t = threadIdx.x;
  int i = blockIdx.x * 256 + t;
  int v = (i < N) ? deg[i] : 0;
#pragma unroll
  for (int d = 1; d < 64; d <<= 1) v += __shfl_xor(v, d, 64);
  if ((t & 63) == 0) ws[t >> 6] = v;
  __syncthreads();
  if (t == 0) bsums[blockIdx.x] = ws[0] + ws[1] + ws[2] + ws[3];
}

__global__ __launch_bounds__(256) void k_bscan(int* __restrict__ bsums, int nb) {
  __shared__ int ws[4];
  int t = threadIdx.x;
  int lane = t & 63, w = t >> 6;
  int v = (t < nb) ? bsums[t] : 0;
  int s = v;
#pragma unroll
  for (int d = 1; d < 64; d <<= 1) {
    int u = __shfl_up(s, d, 64);
    if (lane >= d) s += u;
  }
  if (lane == 63) ws[w] = s;
  __syncthreads();
  int woff = 0;
  if (w >= 1) woff += ws[0];
  if (w >= 2) woff += ws[1];
  if (w >= 3) woff += ws[2];
  if (t < nb) bsums[t] = woff + s - v;
}

__global__ __launch_bounds__(256) void k_scan2(const int* __restrict__ deg,
                                               const int* __restrict__ bsums,
                                               int* __restrict__ rowptr,
                                               int* __restrict__ cursor,
                                               int N, int E) {
  __shared__ int ws[4];
  int t = threadIdx.x;
  int lane = t & 63, w = t >> 6;
  int i = blockIdx.x * 256 + t;
  int v = (i < N) ? deg[i] : 0;
  int s = v;
#pragma unroll
  for (int d = 1; d < 64; d <<= 1) {
    int u = __shfl_up(s, d, 64);
    if (lane >= d) s += u;
  }
  if (lane == 63) ws[w] = s;
  __syncthreads();
  int woff = 0;
  if (w >= 1) woff += ws[0];
  if (w >= 2) woff += ws[1];
  if (w >= 3) woff += ws[2];
  int excl = bsums[blockIdx.x] + woff + s - v;
  if (i < N) { rowptr[i] = excl; cursor[i] = excl; }
  if (i == 0) rowptr[N] = E;
}

__global__ __launch_bounds__(256) void k_fill(const int* __restrict__ src,
                                              const int* __restrict__ dst,
                                              int* __restrict__ cursor,
                                              int* __restrict__ csr_src, int E) {
  int e = blockIdx.x * 256 + threadIdx.x;
  if (e < E) {
    int pos = atomicAdd(&cursor[dst[e]], 1);
    csr_src[pos] = src[e];
  }
}

// ---------- fused layer: gather + GRU (+ classifier on last layer) ----------
// block = 512 threads = 8 waves, owns 32 rows.
#define ASTRIDE 136   // 128 + 8 bf16 pad
#define FSTRIDE 132   // fp32 staging stride
__global__ __launch_bounds__(512) void k_layer(const bf16* __restrict__ hbin,
                                               bf16* __restrict__ hbout,
                                               const bf16* __restrict__ Gl,
                                               const bf16* __restrict__ whhb,
                                               const float* __restrict__ bih,
                                               const float* __restrict__ bhh,
                                               const int* __restrict__ rowptr,
                                               const int* __restrict__ csr_src,
                                               const float* __restrict__ lw,
                                               const float* __restrict__ lb,
                                               float* __restrict__ out,  // non-null => last layer
                                               int N) {
  __shared__ bf16 As[32 * ASTRIDE];
  __shared__ bf16 Hs[32 * ASTRIDE];
  __shared__ float Sf[32 * FSTRIDE];   // fp32 staging (last layer) / bf16 staging (others)
  int t = threadIdx.x;
  int w = t >> 6;
  int lane = t & 63;
  int row0 = blockIdx.x * 32;

  // ---- stage own h rows (coalesced): thread t -> row t>>4, chunk t&15 ----
  {
    int rl = t >> 4;
    int cc = t & 15;
    int row = row0 + rl; if (row > N - 1) row = N - 1;
    *(bf16x8*)(&Hs[rl * ASTRIDE + cc * 8]) = ldb8(hbin + (size_t)row * H + cc * 8);
  }

  // ---- prefetch rowptr for this wave's 4 rows (one chain, up-front) ----
  int base = row0 + w * 4;
  int rp[5];
#pragma unroll
  for (int j = 0; j < 5; j++) {
    int rw = base + j; if (rw > N) rw = N;
    rp[j] = rowptr[rw];
  }

  // ---- gather: coalesced index load + shfl distribute + 4-deep row loads ----
  // All __shfl sites execute with the FULL wave active (wave-uniform trip
  // counts); only loads/accumulates are predicated. (Round-1 bug: divergent
  // trip counts made shfl read inactive lanes -> garbage.)
  int e4 = lane >> 4;
  int c = lane & 15;
#pragma unroll
  for (int rr = 0; rr < 4; rr++) {
    int row = base + rr;                 // wave-uniform
    float acc[8];
#pragma unroll
    for (int j = 0; j < 8; j++) acc[j] = 0.f;
    if (row < N) {                       // wave-uniform branch
      int rb = rp[rr], re = rp[rr + 1];  // wave-uniform
      for (int b0 = rb; b0 < re; b0 += 64) {
        int n = re - b0; if (n > 64) n = 64;          // wave-uniform
        int idx = (lane < n) ? csr_src[b0 + lane] : 0; // ONE coalesced load
        int nf = n & ~15;                              // full 16-edge blocks
        // main loop: trip count nf/16 identical for all lanes (e4 < 16)
        for (int s = e4; s < nf; s += 16) {
          int i0 = __shfl(idx, s, 64);
          int i1 = __shfl(idx, s + 4, 64);
          int i2 = __shfl(idx, s + 8, 64);
          int i3 = __shfl(idx, s + 12, 64);
          bf16x8 v0 = ldb8(hbin + (size_t)i0 * H + c * 8);
          bf16x8 v1 = ldb8(hbin + (size_t)i1 * H + c * 8);
          bf16x8 v2 = ldb8(hbin + (size_t)i2 * H + c * 8);
          bf16x8 v3 = ldb8(hbin + (size_t)i3 * H + c * 8);
#pragma unroll
          for (int j = 0; j < 8; j++)
            acc[j] += ((float)v0[j] + (float)v1[j]) + ((float)v2[j] + (float)v3[j]);
        }
        // tail (< 16 edges), wave-uniform entry; shfls with clamped sources
        if (nf < n) {
          int s0 = nf + e4;
          int i0 = __shfl(idx, (s0 < n) ? s0 : 0, 64);
          int i1 = __shfl(idx, (s0 + 4 < n) ? s0 + 4 : 0, 64);
          int i2 = __shfl(idx, (s0 + 8 < n) ? s0 + 8 : 0, 64);
          int i3 = __shfl(idx, (s0 + 12 < n) ? s0 + 12 : 0, 64);
          if (s0 < n) {
            bf16x8 v = ldb8(hbin + (size_t)i0 * H + c * 8);
#pragma unroll
            for (int j = 0; j < 8; j++) acc[j] += (float)v[j];
          }
          if (s0 + 4 < n) {
            bf16x8 v = ldb8(hbin + (size_t)i1 * H + c * 8);
#pragma unroll
            for (int j = 0; j < 8; j++) acc[j] += (float)v[j];
          }
          if (s0 + 8 < n) {
            bf16x8 v = ldb8(hbin + (size_t)i2 * H + c * 8);
#pragma unroll
            for (int j = 0; j < 8; j++) acc[j] += (float)v[j];
          }
          if (s0 + 12 < n) {
            bf16x8 v = ldb8(hbin + (size_t)i3 * H + c * 8);
#pragma unroll
            for (int j = 0; j < 8; j++) acc[j] += (float)v[j];
          }
        }
      }
    }
#pragma unroll
    for (int j = 0; j < 8; j++) {
      acc[j] += __shfl_xor(acc[j], 16, 64);
      acc[j] += __shfl_xor(acc[j], 32, 64);
    }
    if (e4 == 0) {
      int rl = w * 4 + rr;
      bf16x8 o;
#pragma unroll
      for (int j = 0; j < 8; j++) o[j] = (__bf16)acc[j];
      *(bf16x8*)(&As[rl * ASTRIDE + c * 8]) = o;
    }
  }
  __syncthreads();

  // ---- GRU phase (A and h from LDS) ----
  int r = lane & 15, quad = lane >> 4, laneK = quad * 8;
  int col = w * 16 + r;

  f32x4 aIR[2], aIZ[2], aIN[2], aHR[2], aHZ[2], aHN[2];
#pragma unroll
  for (int q = 0; q < 2; q++) {
    aIR[q] = (f32x4){0.f, 0.f, 0.f, 0.f};
    aIZ[q] = aIR[q]; aIN[q] = aIR[q];
    aHR[q] = aIR[q]; aHZ[q] = aIR[q]; aHN[q] = aIR[q];
  }

  size_t wo0 = (size_t)(0 * H + col) * H;
  size_t wo1 = (size_t)(1 * H + col) * H;
  size_t wo2 = (size_t)(2 * H + col) * H;

#pragma unroll
  for (int kb = 0; kb < 4; kb++) {
    int ko = kb * 32 + laneK;
    bf16x8 a0 = *(const bf16x8*)(&As[r * ASTRIDE + ko]);
    bf16x8 a1 = *(const bf16x8*)(&As[(16 + r) * ASTRIDE + ko]);
    bf16x8 h0 = *(const bf16x8*)(&Hs[r * ASTRIDE + ko]);
    bf16x8 h1 = *(const bf16x8*)(&Hs[(16 + r) * ASTRIDE + ko]);
    bf16x8 gr = ldb8(Gl + wo0 + ko);
    aIR[0] = __builtin_amdgcn_mfma_f32_16x16x32_bf16(a0, gr, aIR[0], 0, 0, 0);
    aIR[1] = __builtin_amdgcn_mfma_f32_16x16x32_bf16(a1, gr, aIR[1], 0, 0, 0);
    bf16x8 gz = ldb8(Gl + wo1 + ko);
    aIZ[0] = __builtin_amdgcn_mfma_f32_16x16x32_bf16(a0, gz, aIZ[0], 0, 0, 0);
    aIZ[1] = __builtin_amdgcn_mfma_f32_16x16x32_bf16(a1, gz, aIZ[1], 0, 0, 0);
    bf16x8 gn = ldb8(Gl + wo2 + ko);
    aIN[0] = __builtin_amdgcn_mfma_f32_16x16x32_bf16(a0, gn, aIN[0], 0, 0, 0);
    aIN[1] = __builtin_amdgcn_mfma_f32_16x16x32_bf16(a1, gn, aIN[1], 0, 0, 0);
    bf16x8 ur = ldb8(whhb + wo0 + ko);
    aHR[0] = __builtin_amdgcn_mfma_f32_16x16x32_bf16(h0, ur, aHR[0], 0, 0, 0);
    aHR[1] = __builtin_amdgcn_mfma_f32_16x16x32_bf16(h1, ur, aHR[1], 0, 0, 0);
    bf16x8 uz = ldb8(whhb + wo1 + ko);
    aHZ[0] = __builtin_amdgcn_mfma_f32_16x16x32_bf16(h0, uz, aHZ[0], 0, 0, 0);
    aHZ[1] = __builtin_amdgcn_mfma_f32_16x16x32_bf16(h1, uz, aHZ[1], 0, 0, 0);
    bf16x8 un = ldb8(whhb + wo2 + ko);
    aHN[0] = __builtin_amdgcn_mfma_f32_16x16x32_bf16(h0, un, aHN[0], 0, 0, 0);
    aHN[1] = __builtin_amdgcn_mfma_f32_16x16x32_bf16(h1, un, aHN[1], 0, 0, 0);
  }

  float bir = bih[col], biz = bih[H + col], bin = bih[2 * H + col];
  float bhr = bhh[col], bhz = bhh[H + col], bhn = bhh[2 * H + col];
  bf16* Sb = (bf16*)Sf;
#pragma unroll
  for (int q = 0; q < 2; q++) {
#pragma unroll
    for (int i = 0; i < 4; i++) {
      int lrow = q * 16 + quad * 4 + i;
      int row = row0 + lrow;
      if (row < N) {
        float rg = fsig(aIR[q][i] + bir + aHR[q][i] + bhr);
        float zg = fsig(aIZ[q][i] + biz + aHZ[q][i] + bhz);
        float ng = ftanh(aIN[q][i] + bin + rg * (aHN[q][i] + bhn));
        float hold = __bfloat162float(Hs[lrow * ASTRIDE + col]);
        float hp = (1.f - zg) * ng + zg * hold;
        if (out) Sf[lrow * FSTRIDE + col] = hp;                    // fp32 for classifier
        else Sb[lrow * ASTRIDE + col] = __float2bfloat16(hp);      // bf16 staging
      }
    }
  }
  __syncthreads();

  if (!out) {
    // ---- coalesced h' store: 16 B/lane, 1 KB/wave contiguous ----
    int rl = t >> 4;
    int cc = t & 15;
    int row = row0 + rl;
    if (row < N) {
      bf16x8 v = *(const bf16x8*)(&Sb[rl * ASTRIDE + cc * 8]);
      *(bf16x8*)(hbout + (size_t)row * H + cc * 8) = v;
    }
  } else {
    // ---- fused classifier: wave w handles rows base..base+3 ----
    int cc = lane & 15;          // class
    int q2 = lane >> 4;          // k-quarter
    f32x4 wv[8];
    const float* wrow = lw + (size_t)cc * H + q2 * 32;
#pragma unroll
    for (int k = 0; k < 8; k++) wv[k] = *(const f32x4*)(wrow + k * 4);
    float bias = lb[cc];
#pragma unroll
    for (int rr = 0; rr < 4; rr++) {
      int lrow = w * 4 + rr;
      int row = row0 + lrow;
      if (row >= N) continue;    // wave-uniform
      const float* hrow = &Sf[lrow * FSTRIDE + q2 * 32];
      float p = 0.f;
#pragma unroll
      for (int k = 0; k < 8; k++) {
        f32x4 hv = *(const f32x4*)(hrow + k * 4);
        p += hv[0] * wv[k][0] + hv[1] * wv[k][1] + hv[2] * wv[k][2] + hv[3] * wv[k][3];
      }
      p += __shfl_xor(p, 16, 64);
      p += __shfl_xor(p, 32, 64);
      float z = p + bias;
      float mx = z;
#pragma unroll
      for (int d = 1; d < 16; d <<= 1) mx = fmaxf(mx, __shfl_xor(mx, d, 64));
      float e = expf(z - mx);
      float ssum = e;
#pragma unroll
      for (int d = 1; d < 16; d <<= 1) ssum += __shfl_xor(ssum, d, 64);
      if (q2 == 0) out[(size_t)row * 16 + cc] = z - mx - logf(ssum);
    }
  }
}

extern "C" void kernel_launch(void* const* d_in, const int* in_sizes, int n_in,
                              void* d_out, int out_size, void* d_ws, size_t ws_size,
                              hipStream_t stream) {
  const float* x   = (const float*)d_in[0];
  const int*   ei  = (const int*)d_in[1];
  const float* W   = (const float*)d_in[2];
  const float* wih = (const float*)d_in[3];
  const float* whh = (const float*)d_in[4];
  const float* bih = (const float*)d_in[5];
  const float* bhh = (const float*)d_in[6];
  const float* lw  = (const float*)d_in[7];
  const float* lb  = (const float*)d_in[8];
  float* out = (float*)d_out;

  int N = in_sizes[0] / 64;   // 50000
  int E = in_sizes[1] / 2;    // 800000
  const int* src = ei;
  const int* dst = ei + E;

  size_t NH = (size_t)N * H;
  bf16* hb0  = (bf16*)d_ws;                  // [N,H] bf16 h ping
  bf16* hb1  = hb0 + NH;                     // [N,H] bf16 h pong
  bf16* Gb   = hb1 + NH;                     // [3][3H,H]
  bf16* whhb = Gb + 3 * 3 * H * H;           // [3H,H]
  int* deg     = (int*)(whhb + 3 * H * H);
  int* rowptr  = deg + N;                    // N+1
  int* cursor  = rowptr + N + 1;             // N
  int* bsums   = cursor + N;                 // <=256
  int* csr_src = bsums + 256;                // E

  int nb_e = (E + 255) / 256;
  int nb_n = (N + 255) / 256;

  int totalPrep = (int)NH + 3 * H * H + 3 * 3 * H * H + N;
  k_prep<<<(totalPrep + 255) / 256, 256, 0, stream>>>(x, hb0, whh, whhb, W, wih,
                                                      Gb, deg, N);
  k_count<<<nb_e, 256, 0, stream>>>(dst, deg, E);
  k_bsum<<<nb_n, 256, 0, stream>>>(deg, bsums, N);
  k_bscan<<<1, 256, 0, stream>>>(bsums, nb_n);
  k_scan2<<<nb_n, 256, 0, stream>>>(deg, bsums, rowptr, cursor, N, E);
  k_fill<<<nb_e, 256, 0, stream>>>(src, dst, cursor, csr_src, E);

  int nb_layer = (N + 31) / 32;
  bf16* hbp[2] = {hb0, hb1};
  for (int l = 0; l < 3; l++) {
    bf16* hin  = hbp[l & 1];
    bf16* hout = hbp[(l + 1) & 1];
    k_layer<<<nb_layer, 512, 0, stream>>>(hin, hout, Gb + (size_t)l * 3 * H * H,
                                          whhb, bih, bhh, rowptr, csr_src,
                                          lw, lb, (l == 2) ? out : nullptr, N);
  }
}

// Round 3
// 406.464 us; speedup vs baseline: 1.3070x; 1.1135x over previous
//
#include <hip/hip_runtime.h>
#include <hip/hip_bf16.h>
#include <math.h>

#define H 128

typedef __bf16 bf16x8 __attribute__((ext_vector_type(8)));
typedef float f32x4 __attribute__((ext_vector_type(4)));
typedef __hip_bfloat16 bf16;

__device__ __forceinline__ bf16x8 ldb8(const bf16* p) {
  return *(const bf16x8*)(const void*)p;
}
// 32-bit offset form: lets the compiler use saddr (SGPR base + 32b voffset)
__device__ __forceinline__ bf16x8 ldb8o(const bf16* base, unsigned byteoff) {
  return *(const bf16x8*)(const void*)((const char*)base + byteoff);
}
__device__ __forceinline__ float fsig(float x) {
  return __fdividef(1.f, 1.f + __expf(-x));
}
__device__ __forceinline__ float ftanh(float x) {
  float x2 = fminf(fmaxf(2.f * x, -80.f), 80.f);
  float t = __expf(x2);
  return __fdividef(t - 1.f, t + 1.f);
}

// fused prep: h0 init (zero-pad x), whh->bf16, G = fold(W, w_ih), edge count
// (deg must be zeroed by hipMemsetAsync before this kernel)
__global__ __launch_bounds__(256) void k_prep(const float* __restrict__ x,
                                              bf16* __restrict__ hb,
                                              const float* __restrict__ whh,
                                              bf16* __restrict__ whhb,
                                              const float* __restrict__ W,
                                              const float* __restrict__ wih,
                                              bf16* __restrict__ G,
                                              const int* __restrict__ dst,
                                              int* __restrict__ deg,
                                              int N, int E) {
  int i = blockIdx.x * 256 + threadIdx.x;
  int NH_ = N * H;
  if (i < NH_) {
    int f = i & (H - 1);
    int n = i >> 7;
    hb[i] = __float2bfloat16((f < 64) ? x[n * 64 + f] : 0.f);
    return;
  }
  i -= NH_;
  if (i < 3 * H * H) {
    whhb[i] = __float2bfloat16(whh[i]);
    return;
  }
  i -= 3 * H * H;
  if (i < 3 * 3 * H * H) {
    int l = i / (3 * H * H);
    int r = i % (3 * H * H);
    int j = r >> 7;
    int k = r & (H - 1);
    const float4* a = (const float4*)(wih + (size_t)j * H);
    const float4* b = (const float4*)(W + (size_t)l * H * H + (size_t)k * H);
    float s = 0.f;
#pragma unroll
    for (int q = 0; q < 32; q++) {
      float4 av = a[q], bv = b[q];
      s += av.x * bv.x + av.y * bv.y + av.z * bv.z + av.w * bv.w;
    }
    G[i] = __float2bfloat16(s);
    return;
  }
  i -= 3 * 3 * H * H;
  if (i < E) atomicAdd(&deg[dst[i]], 1);
}

// ---------- CSR build ----------
__global__ __launch_bounds__(256) void k_bsum(const int* __restrict__ deg,
                                              int* __restrict__ bsums, int N) {
  __shared__ int ws[4];
  int t = threadIdx.x;
  int i = blockIdx.x * 256 + t;
  int v = (i < N) ? deg[i] : 0;
#pragma unroll
  for (int d = 1; d < 64; d <<= 1) v += __shfl_xor(v, d, 64);
  if ((t & 63) == 0) ws[t >> 6] = v;
  __syncthreads();
  if (t == 0) bsums[blockIdx.x] = ws[0] + ws[1] + ws[2] + ws[3];
}

__global__ __launch_bounds__(256) void k_bscan(int* __restrict__ bsums, int nb) {
  __shared__ int ws[4];
  int t = threadIdx.x;
  int lane = t & 63, w = t >> 6;
  int v = (t < nb) ? bsums[t] : 0;
  int s = v;
#pragma unroll
  for (int d = 1; d < 64; d <<= 1) {
    int u = __shfl_up(s, d, 64);
    if (lane >= d) s += u;
  }
  if (lane == 63) ws[w] = s;
  __syncthreads();
  int woff = 0;
  if (w >= 1) woff += ws[0];
  if (w >= 2) woff += ws[1];
  if (w >= 3) woff += ws[2];
  if (t < nb) bsums[t] = woff + s - v;
}

__global__ __launch_bounds__(256) void k_scan2(const int* __restrict__ deg,
                                               const int* __restrict__ bsums,
                                               int* __restrict__ rowptr,
                                               int* __restrict__ cursor,
                                               int N, int E) {
  __shared__ int ws[4];
  int t = threadIdx.x;
  int lane = t & 63, w = t >> 6;
  int i = blockIdx.x * 256 + t;
  int v = (i < N) ? deg[i] : 0;
  int s = v;
#pragma unroll
  for (int d = 1; d < 64; d <<= 1) {
    int u = __shfl_up(s, d, 64);
    if (lane >= d) s += u;
  }
  if (lane == 63) ws[w] = s;
  __syncthreads();
  int woff = 0;
  if (w >= 1) woff += ws[0];
  if (w >= 2) woff += ws[1];
  if (w >= 3) woff += ws[2];
  int excl = bsums[blockIdx.x] + woff + s - v;
  if (i < N) { rowptr[i] = excl; cursor[i] = excl; }
  if (i == 0) rowptr[N] = E;
}

__global__ __launch_bounds__(256) void k_fill(const int* __restrict__ src,
                                              const int* __restrict__ dst,
                                              int* __restrict__ cursor,
                                              int* __restrict__ csr_src, int E) {
  int e = blockIdx.x * 256 + threadIdx.x;
  if (e < E) {
    int pos = atomicAdd(&cursor[dst[e]], 1);
    csr_src[pos] = src[e];
  }
}

// ---------- fused layer: gather + GRU (+ classifier on last layer) ----------
// block = 512 threads = 8 waves, owns 32 rows.
#define ASTRIDE 136   // 128 + 8 bf16 pad
#define FSTRIDE 132   // fp32 staging stride
__global__ __launch_bounds__(512) void k_layer(const bf16* __restrict__ hbin,
                                               bf16* __restrict__ hbout,
                                               const bf16* __restrict__ Gl,
                                               const bf16* __restrict__ whhb,
                                               const float* __restrict__ bih,
                                               const float* __restrict__ bhh,
                                               const int* __restrict__ rowptr,
                                               const int* __restrict__ csr_src,
                                               const float* __restrict__ lw,
                                               const float* __restrict__ lb,
                                               float* __restrict__ out,  // non-null => last layer
                                               int N) {
  // Overlaid LDS: As/Hs live through MFMA phase; staging (Sb/Sf) reuses the
  // same region after a barrier. 17408 B total.
  __shared__ bf16 SH[64 * ASTRIDE];
  bf16* As = SH;
  bf16* Hs = SH + 32 * ASTRIDE;
  int t = threadIdx.x;
  int lane = t & 63;
  int wu = __builtin_amdgcn_readfirstlane(t >> 6);   // wave id, scalar
  int row0 = blockIdx.x * 32;

  // ---- stage own h rows (coalesced): thread t -> row t>>4, chunk t&15 ----
  {
    int rl = t >> 4;
    int cc = t & 15;
    int row = row0 + rl; if (row > N - 1) row = N - 1;
    *(bf16x8*)(&Hs[rl * ASTRIDE + cc * 8]) = ldb8(hbin + (size_t)row * H + cc * 8);
  }

  // ---- rowptr for this wave's 4 rows (scalar loads) ----
  int base = row0 + wu * 4;
  int rp[5];
#pragma unroll
  for (int j = 0; j < 5; j++) {
    int rw = base + j; if (rw > N) rw = N;
    rp[j] = rowptr[rw];
  }

  int e4 = lane >> 4;              // quarter-group (edge slot lane)
  int c = lane & 15;               // col chunk
  unsigned coff = (unsigned)c << 4;  // c*16 bytes

  // ---- preload idx (first <=64 edges) for ALL 4 rows: independent loads ----
  int idxr[4];
#pragma unroll
  for (int rr = 0; rr < 4; rr++) {
    int rb = rp[rr];
    int n = rp[rr + 1] - rb; if (n > 64) n = 64;
    idxr[rr] = (lane < n) ? csr_src[rb + lane] : 0;
  }

  float acc[4][8];
#pragma unroll
  for (int rr = 0; rr < 4; rr++)
#pragma unroll
    for (int j = 0; j < 8; j++) acc[rr][j] = 0.f;

  // ---- straight-line gather: 8 slots/row (covers deg<=32), flat DAG.
  // Off-slots load a clamped duplicate address (L1-hot) and are zeroed by
  // the fma scale -> no exec-mask divergence anywhere; shfls all full-wave.
#pragma unroll
  for (int rr = 0; rr < 4; rr++) {
    int n = rp[rr + 1] - rp[rr];
    bf16x8 vv[8];
    float sc[8];
#pragma unroll
    for (int k = 0; k < 8; k++) {
      int s = e4 + 4 * k;
      int on = s < n;
      int ie = __shfl(idxr[rr], on ? s : 0, 64);
      vv[k] = ldb8o(hbin, ((unsigned)ie << 8) | coff);
      sc[k] = on ? 1.f : 0.f;
    }
#pragma unroll
    for (int k = 0; k < 8; k++) {
#pragma unroll
      for (int j = 0; j < 8; j++)
        acc[rr][j] = fmaf(sc[k], (float)vv[k][j], acc[rr][j]);
    }
    // rare slow path: degree > 32 (wave-uniform branch)
    if (n > 32) {
      int hi = (n < 64) ? n : 64;
      for (int s0 = 32; s0 < hi; s0 += 4) {
        int s = s0 + e4;
        int on = s < hi;
        int ie = __shfl(idxr[rr], on ? s : 0, 64);
        bf16x8 v = ldb8o(hbin, ((unsigned)ie << 8) | coff);
        float scl = on ? 1.f : 0.f;
#pragma unroll
        for (int j = 0; j < 8; j++) acc[rr][j] = fmaf(scl, (float)v[j], acc[rr][j]);
      }
      int rb = rp[rr], re = rp[rr + 1];
      for (int b0 = rb + 64; b0 < re; b0 += 64) {
        int n2 = re - b0; if (n2 > 64) n2 = 64;
        int idx2 = (lane < n2) ? csr_src[b0 + lane] : 0;
        for (int s0 = 0; s0 < n2; s0 += 4) {
          int s = s0 + e4;
          int on = s < n2;
          int ie = __shfl(idx2, on ? s : 0, 64);
          bf16x8 v = ldb8o(hbin, ((unsigned)ie << 8) | coff);
          float scl = on ? 1.f : 0.f;
#pragma unroll
          for (int j = 0; j < 8; j++) acc[rr][j] = fmaf(scl, (float)v[j], acc[rr][j]);
        }
      }
    }
  }

  // ---- cross-group reduction + As write ----
#pragma unroll
  for (int rr = 0; rr < 4; rr++) {
#pragma unroll
    for (int j = 0; j < 8; j++) {
      acc[rr][j] += __shfl_xor(acc[rr][j], 16, 64);
      acc[rr][j] += __shfl_xor(acc[rr][j], 32, 64);
    }
    if (e4 == 0) {
      int rl = wu * 4 + rr;
      bf16x8 o;
#pragma unroll
      for (int j = 0; j < 8; j++) o[j] = (__bf16)acc[rr][j];
      *(bf16x8*)(&As[rl * ASTRIDE + c * 8]) = o;
    }
  }
  __syncthreads();

  // ---- GRU phase (A and h from LDS; weights via 32-bit saddr offsets) ----
  int r = lane & 15, quad = lane >> 4, laneK = quad * 8;
  unsigned col = (unsigned)(wu * 16 + r);
  unsigned wg0 = col << 8;               // gate r : col*H*2
  unsigned wg1 = (1u << 15) | wg0;       // gate z : + H*H*2
  unsigned wg2 = (2u << 15) | wg0;       // gate n

  f32x4 aIR[2], aIZ[2], aIN[2], aHR[2], aHZ[2], aHN[2];
#pragma unroll
  for (int q = 0; q < 2; q++) {
    aIR[q] = (f32x4){0.f, 0.f, 0.f, 0.f};
    aIZ[q] = aIR[q]; aIN[q] = aIR[q];
    aHR[q] = aIR[q]; aHZ[q] = aIR[q]; aHN[q] = aIR[q];
  }

#pragma unroll
  for (int kb = 0; kb < 4; kb++) {
    int ko = kb * 32 + laneK;
    unsigned ko2 = (unsigned)(ko << 1);
    bf16x8 a0 = *(const bf16x8*)(&As[r * ASTRIDE + ko]);
    bf16x8 a1 = *(const bf16x8*)(&As[(16 + r) * ASTRIDE + ko]);
    bf16x8 h0 = *(const bf16x8*)(&Hs[r * ASTRIDE + ko]);
    bf16x8 h1 = *(const bf16x8*)(&Hs[(16 + r) * ASTRIDE + ko]);
    bf16x8 gr = ldb8o(Gl, wg0 | ko2);
    aIR[0] = __builtin_amdgcn_mfma_f32_16x16x32_bf16(a0, gr, aIR[0], 0, 0, 0);
    aIR[1] = __builtin_amdgcn_mfma_f32_16x16x32_bf16(a1, gr, aIR[1], 0, 0, 0);
    bf16x8 gz = ldb8o(Gl, wg1 | ko2);
    aIZ[0] = __builtin_amdgcn_mfma_f32_16x16x32_bf16(a0, gz, aIZ[0], 0, 0, 0);
    aIZ[1] = __builtin_amdgcn_mfma_f32_16x16x32_bf16(a1, gz, aIZ[1], 0, 0, 0);
    bf16x8 gn = ldb8o(Gl, wg2 | ko2);
    aIN[0] = __builtin_amdgcn_mfma_f32_16x16x32_bf16(a0, gn, aIN[0], 0, 0, 0);
    aIN[1] = __builtin_amdgcn_mfma_f32_16x16x32_bf16(a1, gn, aIN[1], 0, 0, 0);
    bf16x8 ur = ldb8o(whhb, wg0 | ko2);
    aHR[0] = __builtin_amdgcn_mfma_f32_16x16x32_bf16(h0, ur, aHR[0], 0, 0, 0);
    aHR[1] = __builtin_amdgcn_mfma_f32_16x16x32_bf16(h1, ur, aHR[1], 0, 0, 0);
    bf16x8 uz = ldb8o(whhb, wg1 | ko2);
    aHZ[0] = __builtin_amdgcn_mfma_f32_16x16x32_bf16(h0, uz, aHZ[0], 0, 0, 0);
    aHZ[1] = __builtin_amdgcn_mfma_f32_16x16x32_bf16(h1, uz, aHZ[1], 0, 0, 0);
    bf16x8 un = ldb8o(whhb, wg2 | ko2);
    aHN[0] = __builtin_amdgcn_mfma_f32_16x16x32_bf16(h0, un, aHN[0], 0, 0, 0);
    aHN[1] = __builtin_amdgcn_mfma_f32_16x16x32_bf16(h1, un, aHN[1], 0, 0, 0);
  }

  // ---- epilogue: compute h' into regs (reads Hs), then barrier, then stage ----
  float bir = bih[col], biz = bih[H + col], bin = bih[2 * H + col];
  float bhr = bhh[col], bhz = bhh[H + col], bhn = bhh[2 * H + col];
  float hpv[2][4];
#pragma unroll
  for (int q = 0; q < 2; q++) {
#pragma unroll
    for (int i = 0; i < 4; i++) {
      int lrow = q * 16 + quad * 4 + i;
      float rg = fsig(aIR[q][i] + bir + aHR[q][i] + bhr);
      float zg = fsig(aIZ[q][i] + biz + aHZ[q][i] + bhz);
      float ng = ftanh(aIN[q][i] + bin + rg * (aHN[q][i] + bhn));
      float hold = __bfloat162float(Hs[lrow * ASTRIDE + col]);
      hpv[q][i] = (1.f - zg) * ng + zg * hold;
    }
  }
  __syncthreads();   // all As/Hs reads done; staging may overwrite

  bf16* Sb = SH;               // bf16 staging (non-last)
  float* Sf = (float*)SH;      // fp32 staging (last layer), 16896 B <= 17408
#pragma unroll
  for (int q = 0; q < 2; q++) {
#pragma unroll
    for (int i = 0; i < 4; i++) {
      int lrow = q * 16 + quad * 4 + i;
      if (out) Sf[lrow * FSTRIDE + col] = hpv[q][i];
      else Sb[lrow * ASTRIDE + col] = __float2bfloat16(hpv[q][i]);
    }
  }
  __syncthreads();

  if (!out) {
    // ---- coalesced h' store: 16 B/lane, 1 KB/wave contiguous ----
    int rl = t >> 4;
    int cc = t & 15;
    int row = row0 + rl;
    if (row < N) {
      bf16x8 v = *(const bf16x8*)(&Sb[rl * ASTRIDE + cc * 8]);
      *(bf16x8*)(hbout + (size_t)row * H + cc * 8) = v;
    }
  } else {
    // ---- fused classifier: wave w handles rows base..base+3 ----
    int cc = lane & 15;          // class
    int q2 = lane >> 4;          // k-quarter
    f32x4 wv[8];
    const float* wrow = lw + (size_t)cc * H + q2 * 32;
#pragma unroll
    for (int k = 0; k < 8; k++) wv[k] = *(const f32x4*)(wrow + k * 4);
    float bias = lb[cc];
#pragma unroll
    for (int rr = 0; rr < 4; rr++) {
      int lrow = wu * 4 + rr;
      int row = row0 + lrow;
      if (row >= N) continue;    // wave-uniform
      const float* hrow = &Sf[lrow * FSTRIDE + q2 * 32];
      float p = 0.f;
#pragma unroll
      for (int k = 0; k < 8; k++) {
        f32x4 hv = *(const f32x4*)(hrow + k * 4);
        p += hv[0] * wv[k][0] + hv[1] * wv[k][1] + hv[2] * wv[k][2] + hv[3] * wv[k][3];
      }
      p += __shfl_xor(p, 16, 64);
      p += __shfl_xor(p, 32, 64);
      float z = p + bias;
      float mx = z;
#pragma unroll
      for (int d = 1; d < 16; d <<= 1) mx = fmaxf(mx, __shfl_xor(mx, d, 64));
      float e = expf(z - mx);
      float ssum = e;
#pragma unroll
      for (int d = 1; d < 16; d <<= 1) ssum += __shfl_xor(ssum, d, 64);
      if (q2 == 0) out[(size_t)row * 16 + cc] = z - mx - logf(ssum);
    }
  }
}

extern "C" void kernel_launch(void* const* d_in, const int* in_sizes, int n_in,
                              void* d_out, int out_size, void* d_ws, size_t ws_size,
                              hipStream_t stream) {
  const float* x   = (const float*)d_in[0];
  const int*   ei  = (const int*)d_in[1];
  const float* W   = (const float*)d_in[2];
  const float* wih = (const float*)d_in[3];
  const float* whh = (const float*)d_in[4];
  const float* bih = (const float*)d_in[5];
  const float* bhh = (const float*)d_in[6];
  const float* lw  = (const float*)d_in[7];
  const float* lb  = (const float*)d_in[8];
  float* out = (float*)d_out;

  int N = in_sizes[0] / 64;   // 50000
  int E = in_sizes[1] / 2;    // 800000
  const int* src = ei;
  const int* dst = ei + E;

  size_t NH = (size_t)N * H;
  bf16* hb0  = (bf16*)d_ws;                  // [N,H] bf16 h ping
  bf16* hb1  = hb0 + NH;                     // [N,H] bf16 h pong
  bf16* Gb   = hb1 + NH;                     // [3][3H,H]
  bf16* whhb = Gb + 3 * 3 * H * H;           // [3H,H]
  int* deg     = (int*)(whhb + 3 * H * H);
  int* rowptr  = deg + N;                    // N+1
  int* cursor  = rowptr + N + 1;             // N
  int* bsums   = cursor + N;                 // <=256
  int* csr_src = bsums + 256;                // E

  int nb_e = (E + 255) / 256;
  int nb_n = (N + 255) / 256;

  hipMemsetAsync(deg, 0, (size_t)N * sizeof(int), stream);
  int totalPrep = (int)NH + 3 * H * H + 3 * 3 * H * H + E;
  k_prep<<<(totalPrep + 255) / 256, 256, 0, stream>>>(x, hb0, whh, whhb, W, wih,
                                                      Gb, dst, deg, N, E);
  k_bsum<<<nb_n, 256, 0, stream>>>(deg, bsums, N);
  k_bscan<<<1, 256, 0, stream>>>(bsums, nb_n);
  k_scan2<<<nb_n, 256, 0, stream>>>(deg, bsums, rowptr, cursor, N, E);
  k_fill<<<nb_e, 256, 0, stream>>>(src, dst, cursor, csr_src, E);

  int nb_layer = (N + 31) / 32;
  bf16* hbp[2] = {hb0, hb1};
  for (int l = 0; l < 3; l++) {
    bf16* hin  = hbp[l & 1];
    bf16* hout = hbp[(l + 1) & 1];
    k_layer<<<nb_layer, 512, 0, stream>>>(hin, hout, Gb + (size_t)l * 3 * H * H,
                                          whhb, bih, bhh, rowptr, csr_src,
                                          lw, lb, (l == 2) ? out : nullptr, N);
  }
}